// Round 2
// baseline (155.324 us; speedup 1.0000x reference)
//
#include <hip/hip_runtime.h>
#include <math.h>

typedef __bf16 bf16;
typedef __attribute__((ext_vector_type(8))) __bf16 bf16x8;
typedef __attribute__((ext_vector_type(4))) float f32x4;

#define N_SEQ 4096
#define NEGINF -1e30f

// async global->LDS, 16B per lane. LDS dest is wave-uniform base + lane*16;
// global src is per-lane (carries the inverse swizzle).
__device__ __forceinline__ void gl_lds16(const void* g, void* l) {
    __builtin_amdgcn_global_load_lds(
        (const __attribute__((address_space(1))) void*)g,
        (__attribute__((address_space(3))) void*)l, 16, 0, 0);
}

// read one MFMA fragment (8 contiguous bf16) from a [rows][64] bf16 LDS tile
// stored with granule XOR swizzle: granule position p holds original granule
// p ^ (row&7).  g = desired original granule (k/8).
__device__ __forceinline__ bf16x8 frag64(const bf16* base, int row, int g) {
    return *(const bf16x8*)(base + (row << 6) + ((g ^ (row & 7)) << 3));
}

// ---------------------------------------------------------------------------
// cast x (fp32 [8192][512]) -> bf16, same layout. 8 elems/thread.
// ---------------------------------------------------------------------------
__global__ __launch_bounds__(256) void cast_x_k(const float* __restrict__ x,
                                                bf16* __restrict__ xb) {
    int idx = blockIdx.x * 256 + threadIdx.x;
    const float4* xv = (const float4*)x;
    float4 a = xv[idx * 2], b = xv[idx * 2 + 1];
    bf16x8 o;
    o[0] = (bf16)a.x; o[1] = (bf16)a.y; o[2] = (bf16)a.z; o[3] = (bf16)a.w;
    o[4] = (bf16)b.x; o[5] = (bf16)b.y; o[6] = (bf16)b.z; o[7] = (bf16)b.w;
    ((bf16x8*)xb)[idx] = o;
}

// ---------------------------------------------------------------------------
// transpose 4 weights: W fp32 [512][512] row-major [k][n] -> Wt bf16 [n][k]
// ---------------------------------------------------------------------------
__global__ __launch_bounds__(256) void transpose_w_k(
    const float* __restrict__ W0, const float* __restrict__ W1,
    const float* __restrict__ W2, const float* __restrict__ W3,
    bf16* __restrict__ T0, bf16* __restrict__ T1,
    bf16* __restrict__ T2, bf16* __restrict__ T3) {
    const int z = blockIdx.z;
    const float* W = (z == 0) ? W0 : (z == 1) ? W1 : (z == 2) ? W2 : W3;
    bf16* T = (z == 0) ? T0 : (z == 1) ? T1 : (z == 2) ? T2 : T3;
    __shared__ bf16 tile[64][65];
    const int t = threadIdx.x;
    const int k0 = blockIdx.x << 6, n0 = blockIdx.y << 6;
#pragma unroll
    for (int i = 0; i < 16; i++) {
        int idx = (i << 8) + t;
        int r = idx >> 6, c = idx & 63;
        tile[r][c] = (bf16)W[(size_t)(k0 + r) * 512 + n0 + c];
    }
    __syncthreads();
#pragma unroll
    for (int i = 0; i < 16; i++) {
        int idx = (i << 8) + t;
        int r = idx >> 6, c = idx & 63;
        T[(size_t)(n0 + r) * 512 + k0 + c] = tile[c][r];
    }
}

// ---------------------------------------------------------------------------
// bf16 MFMA GEMM: C[8192 x 512] = A[8192 x 512] * Bt^T (+ bias)
//   A bf16 row-major [m][k], Bt bf16 [n][k] (W transposed), bias fp32 [n].
// Tile 128x128, BK=64, 4 waves (2x2 quadrants of 64x64), 16x16x32 MFMA.
// LDS double-buffered, global_load_lds(16B) with XOR granule swizzle
// (linear LDS dest + inverse-swizzled global source).
// OUT 0: bf16 head-split [B,H,N,64]; OUT 1: bf16 row-major; OUT 2: fp32 row-major
// ---------------------------------------------------------------------------
template <int OUT>
__global__ __launch_bounds__(256) void gemm_bf16_k(
    const bf16* __restrict__ A, const bf16* __restrict__ Bt,
    const float* __restrict__ bias, void* __restrict__ Cout) {
    __shared__ bf16 sA[2][8192];  // [buf][128 rows][64 k]
    __shared__ bf16 sB[2][8192];
    const int t = threadIdx.x;
    const int lane = t & 63, wid = t >> 6;
    const int wr = wid >> 1, wc = wid & 1;
    const int m0 = blockIdx.x << 7, n0 = blockIdx.y << 7;

    f32x4 acc[4][4] = {};

    const bf16* Ag = A + ((size_t)m0 << 9);
    const bf16* Bg = Bt + ((size_t)n0 << 9);

    // prologue: stage kt=0 into buf 0
#pragma unroll
    for (int i = 0; i < 4; i++) {
        int gid = (i << 8) + t;
        int row = gid >> 3, gs = ((gid & 7) ^ (row & 7)) << 3;
        gl_lds16(Ag + ((size_t)row << 9) + gs, &sA[0][gid << 3]);
        gl_lds16(Bg + ((size_t)row << 9) + gs, &sB[0][gid << 3]);
    }
    __syncthreads();  // drains vmcnt

    int buf = 0;
    for (int kt = 0; kt < 8; kt++) {
        if (kt < 7) {  // issue next-tile loads into other buffer
            int k0 = (kt + 1) << 6;
#pragma unroll
            for (int i = 0; i < 4; i++) {
                int gid = (i << 8) + t;
                int row = gid >> 3, gs = ((gid & 7) ^ (row & 7)) << 3;
                gl_lds16(Ag + ((size_t)row << 9) + k0 + gs, &sA[buf ^ 1][gid << 3]);
                gl_lds16(Bg + ((size_t)row << 9) + k0 + gs, &sB[buf ^ 1][gid << 3]);
            }
        }
#pragma unroll
        for (int ks = 0; ks < 2; ks++) {
            int g = (ks << 2) + (lane >> 4);
            bf16x8 af[4], bfr[4];
#pragma unroll
            for (int mi = 0; mi < 4; mi++)
                af[mi] = frag64(&sA[buf][0], (wr << 6) + (mi << 4) + (lane & 15), g);
#pragma unroll
            for (int ni = 0; ni < 4; ni++)
                bfr[ni] = frag64(&sB[buf][0], (wc << 6) + (ni << 4) + (lane & 15), g);
#pragma unroll
            for (int mi = 0; mi < 4; mi++)
#pragma unroll
                for (int ni = 0; ni < 4; ni++)
                    acc[mi][ni] = __builtin_amdgcn_mfma_f32_16x16x32_bf16(
                        af[mi], bfr[ni], acc[mi][ni], 0, 0, 0);
        }
        __syncthreads();  // staged loads drained; safe to swap
        buf ^= 1;
    }

    // epilogue
#pragma unroll
    for (int mi = 0; mi < 4; mi++) {
#pragma unroll
        for (int ni = 0; ni < 4; ni++) {
            int grow0 = m0 + (wr << 6) + (mi << 4) + ((lane >> 4) << 2);
            int gcol = n0 + (wc << 6) + (ni << 4) + (lane & 15);
            float bb = bias[gcol];
#pragma unroll
            for (int r = 0; r < 4; r++) {
                int grow = grow0 + r;
                float v = acc[mi][ni][r] + bb;
                if (OUT == 0) {
                    int b = grow >> 12, n = grow & 4095;
                    int h = gcol >> 6, d = gcol & 63;
                    size_t idx = ((size_t)(((b << 3) + h) * 4096 + n) << 6) + d;
                    ((bf16*)Cout)[idx] = (bf16)v;
                } else if (OUT == 1) {
                    ((bf16*)Cout)[((size_t)grow << 9) + gcol] = (bf16)v;
                } else {
                    ((float*)Cout)[((size_t)grow << 9) + gcol] = v;
                }
            }
        }
    }
}

// ---------------------------------------------------------------------------
// Windowed flash attention, bf16 MFMA.  Q,K,V bf16 [B*H][4096][64].
// Block = 256 thr (4 waves), Q-tile 64 rows (16 per wave), key chunks of 64,
// window |i-j| <= 128 -> at most 5 chunks.  O bf16 [B][4096][512] row-major.
// ---------------------------------------------------------------------------
__global__ __launch_bounds__(256) void attn_bf16_k(
    const bf16* __restrict__ Q, const bf16* __restrict__ K,
    const bf16* __restrict__ V, bf16* __restrict__ O) {
    __shared__ bf16 QP[4096];  // Q tile, then reused as per-wave P bands
    __shared__ bf16 Ks[4096];  // K chunk [key][64], swizzled
    __shared__ bf16 VT[4096];  // V chunk transposed [d][key], swizzled

    const int t = threadIdx.x;
    const int lane = t & 63, wid = t >> 6;
    const int bh = blockIdx.x >> 6;
    const int q0 = (blockIdx.x & 63) << 6;

    const bf16* Qp = Q + ((size_t)bh << 18);
    const bf16* Kp = K + ((size_t)bh << 18);
    const bf16* Vp = V + ((size_t)bh << 18);

    // stage Q tile (swizzled source, linear LDS)
#pragma unroll
    for (int i = 0; i < 2; i++) {
        int gid = (i << 8) + t;
        int row = gid >> 3, gs = ((gid & 7) ^ (row & 7)) << 3;
        gl_lds16(Qp + ((size_t)(q0 + row) << 6) + gs, &QP[gid << 3]);
    }
    __syncthreads();

    // hoist Q fragments to registers (wave-private rows)
    bf16x8 aq[2];
#pragma unroll
    for (int ks = 0; ks < 2; ks++)
        aq[ks] = frag64(QP, (wid << 4) + (lane & 15), (ks << 2) + (lane >> 4));

    float mrun[4], lrun[4];
    f32x4 acc_o[4] = {};
#pragma unroll
    for (int r = 0; r < 4; r++) { mrun[r] = NEGINF; lrun[r] = 0.f; }

    const int cstart = (q0 >= 128) ? q0 - 128 : 0;
    const int cend = (q0 + 192 <= N_SEQ) ? q0 + 192 : N_SEQ;
    bf16* Pw = &QP[wid << 10];  // wave-private 16x64 P band

    for (int c0 = cstart; c0 < cend; c0 += 64) {
        __syncthreads();  // previous compute done reading Ks/VT
        // stage K chunk
#pragma unroll
        for (int i = 0; i < 2; i++) {
            int gid = (i << 8) + t;
            int row = gid >> 3, gs = ((gid & 7) ^ (row & 7)) << 3;
            gl_lds16(Kp + ((size_t)(c0 + row) << 6) + gs, &Ks[gid << 3]);
        }
        // stage V transposed: VT[d][key] (reg-staged, swizzled writes)
        {
            int key = t >> 2;
            int gd0 = (t & 3) << 1;
            const uint4* vs = (const uint4*)(Vp + ((size_t)(c0 + key) << 6));
            union { uint4 u; bf16 h[8]; } u0, u1;
            u0.u = vs[gd0]; u1.u = vs[gd0 + 1];
#pragma unroll
            for (int e = 0; e < 8; e++) {
                int d0 = (gd0 << 3) + e;
                VT[(d0 << 6) + (((key >> 3) ^ (d0 & 7)) << 3) + (key & 7)] = u0.h[e];
                int d1 = d0 + 8;
                VT[(d1 << 6) + (((key >> 3) ^ (d1 & 7)) << 3) + (key & 7)] = u1.h[e];
            }
        }
        __syncthreads();  // stage complete

        // S = Q K^T for this wave's 16-row band
        f32x4 s[4] = {};
#pragma unroll
        for (int ks = 0; ks < 2; ks++) {
            int g = (ks << 2) + (lane >> 4);
#pragma unroll
            for (int ni = 0; ni < 4; ni++) {
                bf16x8 bk = frag64(Ks, (ni << 4) + (lane & 15), g);
                s[ni] = __builtin_amdgcn_mfma_f32_16x16x32_bf16(aq[ks], bk, s[ni], 0, 0, 0);
            }
        }

        // mask + online softmax + P (bf16) to wave-private LDS band
#pragma unroll
        for (int r = 0; r < 4; r++) {
            int rowl = ((lane >> 4) << 2) + r;
            int qi = q0 + (wid << 4) + rowl;
            float v[4];
#pragma unroll
            for (int ni = 0; ni < 4; ni++) {
                int kj = c0 + (ni << 4) + (lane & 15);
                int dd = qi - kj;
                v[ni] = (dd <= 128 && dd >= -128) ? s[ni][r] * 0.125f : NEGINF;
            }
            float mx = fmaxf(fmaxf(v[0], v[1]), fmaxf(v[2], v[3]));
#pragma unroll
            for (int off = 1; off < 16; off <<= 1)
                mx = fmaxf(mx, __shfl_xor(mx, off));
            float mn = fmaxf(mrun[r], mx);
            float alpha = __expf(mrun[r] - mn);
            float rs = 0.f;
#pragma unroll
            for (int ni = 0; ni < 4; ni++) {
                float p = __expf(v[ni] - mn);
                rs += p;
                int col = (ni << 4) + (lane & 15);
                Pw[(rowl << 6) + (((col >> 3) ^ (rowl & 7)) << 3) + (col & 7)] = (bf16)p;
            }
#pragma unroll
            for (int off = 1; off < 16; off <<= 1)
                rs += __shfl_xor(rs, off);
            mrun[r] = mn;
            lrun[r] = lrun[r] * alpha + rs;
#pragma unroll
            for (int nd = 0; nd < 4; nd++) acc_o[nd][r] *= alpha;
        }

        // O += P V (A = P band from LDS, B = VT)
#pragma unroll
        for (int ks = 0; ks < 2; ks++) {
            int g = (ks << 2) + (lane >> 4);
            bf16x8 pa = frag64(Pw, lane & 15, g);
#pragma unroll
            for (int nd = 0; nd < 4; nd++) {
                bf16x8 bv = frag64(VT, (nd << 4) + (lane & 15), g);
                acc_o[nd] = __builtin_amdgcn_mfma_f32_16x16x32_bf16(pa, bv, acc_o[nd], 0, 0, 0);
            }
        }
    }

    // epilogue: normalize, write O as [B][N][H*64] bf16
    const int b = bh >> 3, h = bh & 7;
    float inv[4];
#pragma unroll
    for (int r = 0; r < 4; r++) inv[r] = 1.f / lrun[r];
#pragma unroll
    for (int nd = 0; nd < 4; nd++) {
#pragma unroll
        for (int r = 0; r < 4; r++) {
            int n = q0 + (wid << 4) + ((lane >> 4) << 2) + r;
            int d = (nd << 4) + (lane & 15);
            O[(((size_t)(b * 4096 + n)) << 9) + (h << 6) + d] =
                (bf16)(acc_o[nd][r] * inv[r]);
        }
    }
}

extern "C" void kernel_launch(void* const* d_in, const int* in_sizes, int n_in,
                              void* d_out, int out_size, void* d_ws, size_t ws_size,
                              hipStream_t stream) {
    (void)in_sizes; (void)n_in; (void)out_size; (void)ws_size;
    const float* x   = (const float*)d_in[0];
    const float* Wq  = (const float*)d_in[1];
    const float* bq  = (const float*)d_in[2];
    const float* Wk  = (const float*)d_in[3];
    const float* bk  = (const float*)d_in[4];
    const float* Wv  = (const float*)d_in[5];
    const float* bv  = (const float*)d_in[6];
    const float* Wfc = (const float*)d_in[7];
    const float* bfc = (const float*)d_in[8];

    bf16* xb  = (bf16*)d_ws;                       // [8192][512]
    bf16* Wtq = xb + (size_t)8192 * 512;           // [512][512] each
    bf16* Wtk = Wtq + 512 * 512;
    bf16* Wtv = Wtk + 512 * 512;
    bf16* Wtf = Wtv + 512 * 512;
    bf16* Qb  = Wtf + 512 * 512;                   // [16][4096][64] each
    bf16* Kb  = Qb + (size_t)16 * 4096 * 64;
    bf16* Vb  = Kb + (size_t)16 * 4096 * 64;
    bf16* Ob  = Vb + (size_t)16 * 4096 * 64;       // [8192][512]

    cast_x_k<<<(8192 * 512) / (256 * 8), 256, 0, stream>>>(x, xb);
    transpose_w_k<<<dim3(8, 8, 4), 256, 0, stream>>>(Wq, Wk, Wv, Wfc,
                                                     Wtq, Wtk, Wtv, Wtf);
    dim3 gg(64, 4);
    gemm_bf16_k<0><<<gg, 256, 0, stream>>>(xb, Wtq, bq, Qb);
    gemm_bf16_k<0><<<gg, 256, 0, stream>>>(xb, Wtk, bk, Kb);
    gemm_bf16_k<0><<<gg, 256, 0, stream>>>(xb, Wtv, bv, Vb);
    attn_bf16_k<<<1024, 256, 0, stream>>>(Qb, Kb, Vb, Ob);
    gemm_bf16_k<2><<<gg, 256, 0, stream>>>(Ob, Wtf, bfc, d_out);
}

// Round 3
// 148.076 us; speedup vs baseline: 1.0489x; 1.0489x over previous
//
#include <hip/hip_runtime.h>
#include <math.h>

typedef __bf16 bf16;
typedef __attribute__((ext_vector_type(8))) __bf16 bf16x8;
typedef __attribute__((ext_vector_type(4))) float f32x4;

#define N_SEQ 4096
#define NEGINF -1e30f

// async global->LDS, 16B per lane. LDS dest is wave-uniform base + lane*16;
// global src is per-lane (carries the inverse swizzle).
__device__ __forceinline__ void gl_lds16(const void* g, void* l) {
    __builtin_amdgcn_global_load_lds(
        (const __attribute__((address_space(1))) void*)g,
        (__attribute__((address_space(3))) void*)l, 16, 0, 0);
}

// read one MFMA fragment (8 contiguous bf16) from a [rows][64] bf16 LDS tile
// stored with granule XOR swizzle: granule position p holds original granule
// p ^ (row&7).
__device__ __forceinline__ bf16x8 frag64(const bf16* base, int row, int g) {
    return *(const bf16x8*)(base + (row << 6) + ((g ^ (row & 7)) << 3));
}

// ---------------------------------------------------------------------------
// cast x (fp32 [8192][512]) -> bf16, same layout. 8 elems/thread.
// ---------------------------------------------------------------------------
__global__ __launch_bounds__(256) void cast_x_k(const float* __restrict__ x,
                                                bf16* __restrict__ xb) {
    int idx = blockIdx.x * 256 + threadIdx.x;
    const float4* xv = (const float4*)x;
    float4 a = xv[idx * 2], b = xv[idx * 2 + 1];
    bf16x8 o;
    o[0] = (bf16)a.x; o[1] = (bf16)a.y; o[2] = (bf16)a.z; o[3] = (bf16)a.w;
    o[4] = (bf16)b.x; o[5] = (bf16)b.y; o[6] = (bf16)b.z; o[7] = (bf16)b.w;
    ((bf16x8*)xb)[idx] = o;
}

// ---------------------------------------------------------------------------
// prep: Wcat bf16 [2048][512] = [Wq^T; Wk^T; Wv^T; Wfc^T], bcat fp32 [2048].
// grid (8, 32): k0 = bx*64, n0 = by*64 (global col in 0..2048).
// ---------------------------------------------------------------------------
__global__ __launch_bounds__(256) void prep_w_k(
    const float* __restrict__ Wq, const float* __restrict__ bq,
    const float* __restrict__ Wk, const float* __restrict__ bk,
    const float* __restrict__ Wv, const float* __restrict__ bv,
    const float* __restrict__ Wfc, const float* __restrict__ bfc,
    bf16* __restrict__ Wcat, float* __restrict__ bcat) {
    const int t = threadIdx.x;
    const int k0 = blockIdx.x << 6, n0 = blockIdx.y << 6;
    const int sel = n0 >> 9, nloc = n0 & 511;
    const float* W = (sel == 0) ? Wq : (sel == 1) ? Wk : (sel == 2) ? Wv : Wfc;
    const float* bi = (sel == 0) ? bq : (sel == 1) ? bk : (sel == 2) ? bv : bfc;
    __shared__ bf16 tile[64][65];
#pragma unroll
    for (int i = 0; i < 16; i++) {
        int idx = (i << 8) + t;
        int r = idx >> 6, c = idx & 63;
        tile[r][c] = (bf16)W[(size_t)(k0 + r) * 512 + nloc + c];
    }
    __syncthreads();
#pragma unroll
    for (int i = 0; i < 16; i++) {
        int idx = (i << 8) + t;
        int r = idx >> 6, c = idx & 63;
        Wcat[(size_t)(n0 + r) * 512 + k0 + c] = tile[c][r];
    }
    if (blockIdx.x == 0 && t < 64) bcat[n0 + t] = bi[nloc + t];
}

// ---------------------------------------------------------------------------
// bf16 MFMA GEMM: C[8192 x Nc] = A[8192 x 512] * Bt^T (+ bias)
//   A bf16 row-major [m][k], Bt bf16 [n][k], bias fp32 (already offset).
// Tile 128 x BN, BK=64, 4 waves (2x2), wave tile 64 x BN/2, 16x16x32 MFMA.
// LDS double-buffered, global_load_lds(16B), XOR granule swizzle.
// OUT 0: bf16 QKV head-split [3][B][H][N][64]; OUT 1: fp32 row-major [m][512].
// ---------------------------------------------------------------------------
template <int OUT, int BN>
__global__ __launch_bounds__(256) void gemm_bf16_k(
    const bf16* __restrict__ A, const bf16* __restrict__ Bt,
    const float* __restrict__ bias, void* __restrict__ Cout) {
    constexpr int NI = BN / 32;       // n-frags per wave
    constexpr int BIT = BN / 32;      // B staging iters (2048 elems each)
    __shared__ bf16 sA[2][128 * 64];
    __shared__ bf16 sB[2][BN * 64];
    const int t = threadIdx.x;
    const int lane = t & 63, wid = t >> 6;
    const int wr = wid >> 1, wc = wid & 1;
    const int m0 = blockIdx.x << 7;
    const int n0 = blockIdx.y * BN;

    f32x4 acc[4][NI] = {};

    const bf16* Ag = A + ((size_t)m0 << 9);
    const bf16* Bg = Bt + ((size_t)n0 << 9);

#define STAGE(buf, k0)                                                      \
    {                                                                       \
        _Pragma("unroll") for (int i = 0; i < 4; i++) {                     \
            int gid = (i << 8) + t;                                         \
            int row = gid >> 3, gs = ((gid & 7) ^ (row & 7)) << 3;          \
            gl_lds16(Ag + ((size_t)row << 9) + (k0) + gs, &sA[buf][gid << 3]); \
        }                                                                   \
        _Pragma("unroll") for (int i = 0; i < BIT; i++) {                   \
            int gid = (i << 8) + t;                                         \
            int row = gid >> 3, gs = ((gid & 7) ^ (row & 7)) << 3;          \
            gl_lds16(Bg + ((size_t)row << 9) + (k0) + gs, &sB[buf][gid << 3]); \
        }                                                                   \
    }

    STAGE(0, 0);
    __syncthreads();

    int buf = 0;
    for (int kt = 0; kt < 8; kt++) {
        if (kt < 7) STAGE(buf ^ 1, (kt + 1) << 6);
#pragma unroll
        for (int ks = 0; ks < 2; ks++) {
            int g = (ks << 2) + (lane >> 4);
            bf16x8 af[4], bfr[NI];
#pragma unroll
            for (int mi = 0; mi < 4; mi++)
                af[mi] = frag64(&sA[buf][0], (wr << 6) + (mi << 4) + (lane & 15), g);
#pragma unroll
            for (int ni = 0; ni < NI; ni++)
                bfr[ni] = frag64(&sB[buf][0], wc * (BN / 2) + (ni << 4) + (lane & 15), g);
#pragma unroll
            for (int mi = 0; mi < 4; mi++)
#pragma unroll
                for (int ni = 0; ni < NI; ni++)
                    acc[mi][ni] = __builtin_amdgcn_mfma_f32_16x16x32_bf16(
                        af[mi], bfr[ni], acc[mi][ni], 0, 0, 0);
        }
        __syncthreads();
        buf ^= 1;
    }
#undef STAGE

#pragma unroll
    for (int mi = 0; mi < 4; mi++) {
#pragma unroll
        for (int ni = 0; ni < NI; ni++) {
            int grow0 = m0 + (wr << 6) + (mi << 4) + ((lane >> 4) << 2);
            int gcol = n0 + wc * (BN / 2) + (ni << 4) + (lane & 15);
            float bb = bias[gcol];
#pragma unroll
            for (int r = 0; r < 4; r++) {
                int grow = grow0 + r;
                float v = acc[mi][ni][r] + bb;
                if (OUT == 0) {
                    int b = grow >> 12, n = grow & 4095;
                    int sel = gcol >> 9, rem = gcol & 511;
                    int h = rem >> 6, d = rem & 63;
                    size_t idx =
                        (((size_t)((sel << 4) + (b << 3) + h) * 4096 + n) << 6) + d;
                    ((bf16*)Cout)[idx] = (bf16)v;
                } else {
                    ((float*)Cout)[((size_t)grow << 9) + gcol] = v;
                }
            }
        }
    }
}

// ---------------------------------------------------------------------------
// Windowed flash attention, bf16 MFMA.  Q,K,V bf16 [B*H][4096][64].
// Block = 256 thr (4 waves), Q-tile 64 rows (16 per wave), key chunks of 64,
// window |i-j| <= 128 -> at most 5 chunks.  O bf16 [B][4096][512] row-major.
// ---------------------------------------------------------------------------
__global__ __launch_bounds__(256) void attn_bf16_k(
    const bf16* __restrict__ Q, const bf16* __restrict__ K,
    const bf16* __restrict__ V, bf16* __restrict__ O) {
    __shared__ bf16 QP[4096];  // Q tile, then reused as per-wave P bands
    __shared__ bf16 Ks[4096];  // K chunk [key][64], swizzled
    __shared__ bf16 VT[4096];  // V chunk transposed [d][key], swizzled

    const int t = threadIdx.x;
    const int lane = t & 63, wid = t >> 6;
    const int bh = blockIdx.x >> 6;
    const int q0 = (blockIdx.x & 63) << 6;

    const bf16* Qp = Q + ((size_t)bh << 18);
    const bf16* Kp = K + ((size_t)bh << 18);
    const bf16* Vp = V + ((size_t)bh << 18);

#pragma unroll
    for (int i = 0; i < 2; i++) {
        int gid = (i << 8) + t;
        int row = gid >> 3, gs = ((gid & 7) ^ (row & 7)) << 3;
        gl_lds16(Qp + ((size_t)(q0 + row) << 6) + gs, &QP[gid << 3]);
    }
    __syncthreads();

    bf16x8 aq[2];
#pragma unroll
    for (int ks = 0; ks < 2; ks++)
        aq[ks] = frag64(QP, (wid << 4) + (lane & 15), (ks << 2) + (lane >> 4));

    float mrun[4], lrun[4];
    f32x4 acc_o[4] = {};
#pragma unroll
    for (int r = 0; r < 4; r++) { mrun[r] = NEGINF; lrun[r] = 0.f; }

    const int cstart = (q0 >= 128) ? q0 - 128 : 0;
    const int cend = (q0 + 192 <= N_SEQ) ? q0 + 192 : N_SEQ;
    bf16* Pw = &QP[wid << 10];

    for (int c0 = cstart; c0 < cend; c0 += 64) {
        __syncthreads();
#pragma unroll
        for (int i = 0; i < 2; i++) {
            int gid = (i << 8) + t;
            int row = gid >> 3, gs = ((gid & 7) ^ (row & 7)) << 3;
            gl_lds16(Kp + ((size_t)(c0 + row) << 6) + gs, &Ks[gid << 3]);
        }
        {
            int key = t >> 2;
            int gd0 = (t & 3) << 1;
            const uint4* vs = (const uint4*)(Vp + ((size_t)(c0 + key) << 6));
            union { uint4 u; bf16 h[8]; } u0, u1;
            u0.u = vs[gd0]; u1.u = vs[gd0 + 1];
#pragma unroll
            for (int e = 0; e < 8; e++) {
                int d0 = (gd0 << 3) + e;
                VT[(d0 << 6) + (((key >> 3) ^ (d0 & 7)) << 3) + (key & 7)] = u0.h[e];
                int d1 = d0 + 8;
                VT[(d1 << 6) + (((key >> 3) ^ (d1 & 7)) << 3) + (key & 7)] = u1.h[e];
            }
        }
        __syncthreads();

        f32x4 s[4] = {};
#pragma unroll
        for (int ks = 0; ks < 2; ks++) {
            int g = (ks << 2) + (lane >> 4);
#pragma unroll
            for (int ni = 0; ni < 4; ni++) {
                bf16x8 bk = frag64(Ks, (ni << 4) + (lane & 15), g);
                s[ni] = __builtin_amdgcn_mfma_f32_16x16x32_bf16(aq[ks], bk, s[ni], 0, 0, 0);
            }
        }

#pragma unroll
        for (int r = 0; r < 4; r++) {
            int rowl = ((lane >> 4) << 2) + r;
            int qi = q0 + (wid << 4) + rowl;
            float v[4];
#pragma unroll
            for (int ni = 0; ni < 4; ni++) {
                int kj = c0 + (ni << 4) + (lane & 15);
                int dd = qi - kj;
                v[ni] = (dd <= 128 && dd >= -128) ? s[ni][r] * 0.125f : NEGINF;
            }
            float mx = fmaxf(fmaxf(v[0], v[1]), fmaxf(v[2], v[3]));
#pragma unroll
            for (int off = 1; off < 16; off <<= 1)
                mx = fmaxf(mx, __shfl_xor(mx, off));
            float mn = fmaxf(mrun[r], mx);
            float alpha = __expf(mrun[r] - mn);
            float rs = 0.f;
#pragma unroll
            for (int ni = 0; ni < 4; ni++) {
                float p = __expf(v[ni] - mn);
                rs += p;
                int col = (ni << 4) + (lane & 15);
                Pw[(rowl << 6) + (((col >> 3) ^ (rowl & 7)) << 3) + (col & 7)] = (bf16)p;
            }
#pragma unroll
            for (int off = 1; off < 16; off <<= 1)
                rs += __shfl_xor(rs, off);
            mrun[r] = mn;
            lrun[r] = lrun[r] * alpha + rs;
#pragma unroll
            for (int nd = 0; nd < 4; nd++) acc_o[nd][r] *= alpha;
        }

#pragma unroll
        for (int ks = 0; ks < 2; ks++) {
            int g = (ks << 2) + (lane >> 4);
            bf16x8 pa = frag64(Pw, lane & 15, g);
#pragma unroll
            for (int nd = 0; nd < 4; nd++) {
                bf16x8 bv = frag64(VT, (nd << 4) + (lane & 15), g);
                acc_o[nd] = __builtin_amdgcn_mfma_f32_16x16x32_bf16(pa, bv, acc_o[nd], 0, 0, 0);
            }
        }
    }

    const int b = bh >> 3, h = bh & 7;
    float inv[4];
#pragma unroll
    for (int r = 0; r < 4; r++) inv[r] = 1.f / lrun[r];
#pragma unroll
    for (int nd = 0; nd < 4; nd++) {
#pragma unroll
        for (int r = 0; r < 4; r++) {
            int n = q0 + (wid << 4) + ((lane >> 4) << 2) + r;
            int d = (nd << 4) + (lane & 15);
            O[(((size_t)(b * 4096 + n)) << 9) + (h << 6) + d] =
                (bf16)(acc_o[nd][r] * inv[r]);
        }
    }
}

extern "C" void kernel_launch(void* const* d_in, const int* in_sizes, int n_in,
                              void* d_out, int out_size, void* d_ws, size_t ws_size,
                              hipStream_t stream) {
    (void)in_sizes; (void)n_in; (void)out_size; (void)ws_size;
    const float* x   = (const float*)d_in[0];
    const float* Wq  = (const float*)d_in[1];
    const float* bq  = (const float*)d_in[2];
    const float* Wk  = (const float*)d_in[3];
    const float* bk  = (const float*)d_in[4];
    const float* Wv  = (const float*)d_in[5];
    const float* bv  = (const float*)d_in[6];
    const float* Wfc = (const float*)d_in[7];
    const float* bfc = (const float*)d_in[8];

    bf16* xb    = (bf16*)d_ws;                       // [8192][512]
    bf16* Wcat  = xb + (size_t)8192 * 512;           // [2048][512]
    float* bcat = (float*)(Wcat + (size_t)2048 * 512);  // [2048]
    bf16* QKVb  = (bf16*)(bcat + 2048);              // [3][16][4096][64]
    bf16* Ob    = QKVb + (size_t)3 * 16 * 4096 * 64; // [8192][512]

    cast_x_k<<<(8192 * 512) / (256 * 8), 256, 0, stream>>>(x, xb);
    prep_w_k<<<dim3(8, 32), 256, 0, stream>>>(Wq, bq, Wk, bk, Wv, bv, Wfc, bfc,
                                              Wcat, bcat);

    // fused QKV: C[8192 x 1536]
    gemm_bf16_k<0, 128><<<dim3(64, 12), 256, 0, stream>>>(xb, Wcat, bcat, QKVb);

    const bf16* Qb = QKVb;
    const bf16* Kb = QKVb + ((size_t)1 << 22);
    const bf16* Vb = QKVb + ((size_t)2 << 22);
    attn_bf16_k<<<1024, 256, 0, stream>>>(Qb, Kb, Vb, Ob);

    // fc: C[8192 x 512] fp32
    gemm_bf16_k<1, 64><<<dim3(64, 8), 256, 0, stream>>>(
        Ob, Wcat + ((size_t)1536 << 9), bcat + 1536, d_out);
}